// Round 9
// baseline (104.421 us; speedup 1.0000x reference)
//
#include <hip/hip_runtime.h>

// CellList — all i<j pairs of N atoms, cutoff 5.2. Output: FLOAT32, flat,
// 7P elements, P = N(N-1)/2:
//   [0,P)    atom_pairs row i
//   [P,2P)   atom_pairs row j
//   [2P,3P)  in_cutoff (1.0/0.0)
//   [3P,6P)  diff [P,3] = (coords[i]-coords[j]) * in_cutoff
//   [6P,7P)  dist = in_cutoff ? ||coords[i]-coords[j]|| : 0
//
// Store-BW bound (528 MB mandatory). Forensics so far:
//  - r6: nontemporal stores defeat L2 write-merge (WRITE 988 MB, 2.4 TB/s).
//  - r7: 8 pairs/thread -> VGPR 124 -> occupancy drop -> 155 us.
//  - r8: diff-stream LDS densification ~neutral (L2 already merges
//    wave-contiguous interleaved stores). 101 us = 5.23 TB/s vs 6.9 fill.
// r9: persistent blocks — grid 1536 (6/CU), 12 tiles of 1024 pairs each,
// removes ~18k-workgroup dispatch overhead as a variable.

__global__ __launch_bounds__(256, 6) void cell_pairs_f32(
    const int* __restrict__ species,
    const float* __restrict__ coords,
    float* __restrict__ out,
    int N, int P, int ntiles)
{
    __shared__ float ldsd[3072];            // 1024 pairs x 3 floats = 12 KB

    const int t = threadIdx.x;
    const int twoNm1 = 2 * N - 1;
    const size_t Ps = (size_t)P;

    for (int tile = blockIdx.x; tile < ntiles; tile += gridDim.x) {
        const int blk = tile << 10;         // 1024 pairs per tile
        const bool full = (blk + 1024 <= P);
        const int p0 = blk + (t << 2);

        // ---- decode (i,j) for first pair p0 ----
        // rows(i) = i*(2N-1-i)/2; exact int64 disc, f32 sqrt, int correction.
        int i = 0, j = 1;
        if (p0 < P) {
            long long disc_i = (long long)twoNm1 * (long long)twoNm1
                             - 8LL * (long long)p0;
            float sr = __fsqrt_rn((float)disc_i);
            i = (int)(((float)twoNm1 - sr) * 0.5f);
            if (i < 0) i = 0;
            if (i > N - 2) i = N - 2;
            long long ri = ((long long)i * (long long)(twoNm1 - i)) >> 1;
            while (i < N - 2) {
                long long rn = ((long long)(i + 1) * (long long)(twoNm1 - (i + 1))) >> 1;
                if (rn <= (long long)p0) { ++i; ri = rn; } else break;
            }
            while (i > 0 && ri > (long long)p0) {
                --i; ri = ((long long)i * (long long)(twoNm1 - i)) >> 1;
            }
            j = i + 1 + (int)((long long)p0 - ri);
        }

        if (full) {
            float cix = coords[3 * i + 0];
            float ciy = coords[3 * i + 1];
            float ciz = coords[3 * i + 2];
            int   si  = species[i];

            float iv[4], jv[4], cv[4], sv[4], dv[12];
#pragma unroll 4
            for (int k = 0; k < 4; ++k) {
                if (j >= N) {
                    ++i; j = i + 1;
                    cix = coords[3 * i + 0];
                    ciy = coords[3 * i + 1];
                    ciz = coords[3 * i + 2];
                    si  = species[i];
                }
                float dx = cix - coords[3 * j + 0];
                float dy = ciy - coords[3 * j + 1];
                float dz = ciz - coords[3 * j + 2];
                // numpy-exact f32: (dx*dx + dy*dy) + dz*dz, no FMA contraction
                float sq = __fadd_rn(__fadd_rn(__fmul_rn(dx, dx), __fmul_rn(dy, dy)),
                                     __fmul_rn(dz, dz));
                float d  = __fsqrt_rn(sq);
                bool inc = (d <= 5.2f) && (si != -1) && (species[j] != -1);
                float m  = inc ? 1.0f : 0.0f;

                iv[k] = (float)i;
                jv[k] = (float)j;
                cv[k] = m;
                sv[k] = __fmul_rn(d, m);
                dv[3 * k + 0] = __fmul_rn(dx, m);
                dv[3 * k + 1] = __fmul_rn(dy, m);
                dv[3 * k + 2] = __fmul_rn(dz, m);
                ++j;
            }

            // diff -> LDS
            float4* lw = reinterpret_cast<float4*>(&ldsd[12 * t]);
            lw[0] = make_float4(dv[0], dv[1], dv[2],  dv[3]);
            lw[1] = make_float4(dv[4], dv[5], dv[6],  dv[7]);
            lw[2] = make_float4(dv[8], dv[9], dv[10], dv[11]);

            // narrow streams direct (dense 16B/lane)
            *reinterpret_cast<float4*>(out + (size_t)p0)
                = make_float4(iv[0], iv[1], iv[2], iv[3]);
            *reinterpret_cast<float4*>(out + Ps + (size_t)p0)
                = make_float4(jv[0], jv[1], jv[2], jv[3]);
            *reinterpret_cast<float4*>(out + 2 * Ps + (size_t)p0)
                = make_float4(cv[0], cv[1], cv[2], cv[3]);
            *reinterpret_cast<float4*>(out + 6 * Ps + (size_t)p0)
                = make_float4(sv[0], sv[1], sv[2], sv[3]);

            __syncthreads();

            // diff writeback: 3 dense chunks of 1024 floats
            const float4* lr = reinterpret_cast<const float4*>(ldsd);
            float4 d0 = lr[t];
            float4 d1 = lr[t + 256];
            float4 d2 = lr[t + 512];
            float* gd = out + 3 * Ps + 3 * (size_t)blk;
            reinterpret_cast<float4*>(gd)[t]        = d0;
            reinterpret_cast<float4*>(gd + 1024)[t] = d1;
            reinterpret_cast<float4*>(gd + 2048)[t] = d2;

            __syncthreads();   // protect LDS before next tile overwrites
        } else {
            // partial tail tile (not hit when P % 1024 == 0): scalar path
            for (int k = 0; k < 4; ++k) {
                int p = p0 + k;
                if (p >= P) break;
                if (j >= N) { ++i; j = i + 1; }
                float dx = coords[3 * i + 0] - coords[3 * j + 0];
                float dy = coords[3 * i + 1] - coords[3 * j + 1];
                float dz = coords[3 * i + 2] - coords[3 * j + 2];
                float sq = __fadd_rn(__fadd_rn(__fmul_rn(dx, dx), __fmul_rn(dy, dy)),
                                     __fmul_rn(dz, dz));
                float d  = __fsqrt_rn(sq);
                bool inc = (d <= 5.2f) && (species[i] != -1) && (species[j] != -1);
                float m  = inc ? 1.0f : 0.0f;
                size_t pp = (size_t)p;
                out[pp]                  = (float)i;
                out[Ps + pp]             = (float)j;
                out[2 * Ps + pp]         = m;
                out[3 * Ps + 3 * pp + 0] = __fmul_rn(dx, m);
                out[3 * Ps + 3 * pp + 1] = __fmul_rn(dy, m);
                out[3 * Ps + 3 * pp + 2] = __fmul_rn(dz, m);
                out[6 * Ps + pp]         = __fmul_rn(d, m);
                ++j;
            }
        }
    }
}

extern "C" void kernel_launch(void* const* d_in, const int* in_sizes, int n_in,
                              void* d_out, int out_size, void* d_ws, size_t ws_size,
                              hipStream_t stream) {
    const int*   species = (const int*)d_in[0];
    const float* coords  = (const float*)d_in[1];
    int N = in_sizes[0];
    long long Pll = (long long)N * (long long)(N - 1) / 2;
    int P = (int)Pll;

    int ntiles = (int)((Pll + 1023) >> 10);     // 1024 pairs per tile
    int grid   = 1536;                           // 6 blocks/CU x 256 CU
    if (grid > ntiles) grid = ntiles;

    cell_pairs_f32<<<dim3((unsigned)grid), dim3(256), 0, stream>>>(
        species, coords, (float*)d_out, N, P, ntiles);
}